// Round 17
// baseline (10292.406 us; speedup 1.0000x reference)
//
#include <hip/hip_runtime.h>
#include <math.h>

#define NN   1024
#define TTL  128
#define NTP  131072   // NN*TTL
#define TOPK 30

// ---- fp64 weight region offsets (in doubles) ----
#define OEGTF_T 0
#define OEGTF_C 48
#define OEGTF_B 96
#define OEGTG_T 112
#define OEGTG_C 160
#define OEGTG_B 208
#define OEE0    224
#define OEE1    736
#define OEE2    1248
#define OEEB    1760
#define OEOUT_W 1792
#define OEOUT_B 3840
#define ODTF_B  16192
#define ODTG_B  28544
#define ODEB    34752
#define OWC     34784
#define OBC     34816
#define ODEALL  59456   // [i][96]: [0:32]=E1, [32:64]=E2, [64:96]=E0 (6144)
#define ODTW2   65600   // folded (tconv.eout): [oc][j=32][96] f taps 0..47, g taps 48..95 (12288)
#define OCF     77888   // f per-tap consts [oc][o][k] (192)
#define OCG     78080   // g per-tap consts (192)
#define WTOT    78272

// ============ setup kernels ============

__global__ void k_prep_weights(
    const float* __restrict__ w_start, const float* __restrict__ b_start,
    const float* __restrict__ etf_w, const float* __restrict__ etf_b,
    const float* __restrict__ etg_w, const float* __restrict__ etg_b,
    const float* __restrict__ eg1_w, const float* __restrict__ eg1_b,
    const float* __restrict__ eg2_w, const float* __restrict__ eg2_b,
    const float* __restrict__ eend_w, const float* __restrict__ eend_b,
    const float* __restrict__ eout_w, const float* __restrict__ eout_b,
    const float* __restrict__ dtf_w, const float* __restrict__ dtf_b,
    const float* __restrict__ dtg_w, const float* __restrict__ dtg_b,
    const float* __restrict__ dg1_w, const float* __restrict__ dg1_b,
    const float* __restrict__ dg2_w, const float* __restrict__ dg2_b,
    const float* __restrict__ dend_w, const float* __restrict__ dend_b,
    const float* __restrict__ dout_w, const float* __restrict__ dout_b,
    const float* __restrict__ w_end, const float* __restrict__ b_end,
    double* __restrict__ W)
{
    int tid = blockIdx.x*blockDim.x + threadIdx.x;
    int nthr = gridDim.x*blockDim.x;
    // encoder gate collapsed through w_start: tap[o][k] = sum_i w[o,i,k]*ws[i]
    for (int id=tid; id<96; id+=nthr){
        int which = id/48; int r = id%48; int o = r/3, k = r%3;
        const float* w = which ? etg_w : etf_w;
        double t=0.0, c=0.0;
        for (int i=0;i<16;i++){
            double wv = (double)w[(o*16+i)*3+k];
            t += wv*(double)w_start[i];
            c += wv*(double)b_start[i];
        }
        W[(which?OEGTG_T:OEGTF_T)+o*3+k] = t;
        W[(which?OEGTG_C:OEGTF_C)+o*3+k] = c;
    }
    for (int i=tid;i<16;i+=nthr){
        W[OEGTF_B+i] = (double)etf_b[i];
        W[OEGTG_B+i] = (double)etg_b[i];
    }
    // encoder fused (mix . end) matrices: Ee_k[i][o2] = sum_o eend_w[o2][o]*Mk[i][o]
    for (int id=tid; id<512; id+=nthr){
        int i = id>>5, o2 = id&31;
        double s0=0.0, s1=0.0, s2=0.0;
        for (int o=0;o<16;o++){
            double m0 = (double)eg1_w[o*32+i] + (double)eg2_w[o*32+i]
                      + 0.05*((double)eg1_w[o*32+16+i] + (double)eg2_w[o*32+16+i]);
            double m1 = 0.95*(double)eg1_w[o*32+16+i];
            double m2 = 0.95*(double)eg2_w[o*32+16+i];
            double ew = (double)eend_w[o2*16+o];
            s0 += ew*m0; s1 += ew*m1; s2 += ew*m2;
        }
        W[OEE0+i*32+o2]=s0; W[OEE1+i*32+o2]=s1; W[OEE2+i*32+o2]=s2;
    }
    for (int o2=tid; o2<32; o2+=nthr){
        double s = (double)eend_b[o2];
        for (int o=0;o<16;o++) s += (double)eend_w[o2*16+o]*((double)eg1_b[o]+(double)eg2_b[o]);
        W[OEEB+o2] = s;
    }
    for (int i=tid;i<64;i+=nthr){
        W[ODTF_B+i]=(double)dtf_b[i]; W[ODTG_B+i]=(double)dtg_b[i];
    }
    // folded decoder tconv weights: W'[oc][j][q], q<48: f (o*3+k), q>=48: g
    for (int id=tid; id<12288; id+=nthr){
        int oc = id/3072; int rem = id%3072; int j = rem/96; int q = rem%96;
        const float* w = (q<48) ? dtf_w : dtg_w;
        int q2 = (q<48) ? q : q-48;
        int o = q2/3, k = q2%3;
        double s = 0.0;
        for (int i=0;i<64;i++)
            s += (double)w[((oc*16+o)*64+i)*3+k]*(double)eout_w[i*32+j];
        W[ODTW2+id] = s;
    }
    // per-tap constants from eout_b
    for (int id=tid; id<384; id+=nthr){
        int which = id/192; int r = id%192;
        int oc = r/48; int q = r%48; int o = q/3, k = q%3;
        const float* w = which ? dtg_w : dtf_w;
        double s = 0.0;
        for (int i=0;i<64;i++)
            s += (double)w[((oc*16+o)*64+i)*3+k]*(double)eout_b[i];
        W[(which?OCG:OCF) + oc*48 + o*3 + k] = s;
    }
    // decoder fused (mix . end) matrices, combined layout [i][96]
    for (int id=tid; id<6144; id+=nthr){
        int i = id/96, j = id%96;
        double s = 0.0;
        if (j < 32){
            int o2 = j;
            for (int o=0;o<64;o++){
                double m1 = 0.95*(double)dg1_w[o*128+64+i];
                s += (double)dend_w[o2*64+o]*m1;
            }
        } else if (j < 64){
            int o2 = j-32;
            for (int o=0;o<64;o++){
                double m2 = 0.95*(double)dg2_w[o*128+64+i];
                s += (double)dend_w[o2*64+o]*m2;
            }
        } else {
            int o2 = j-64;
            for (int o=0;o<64;o++){
                double m0 = (double)dg1_w[o*128+i] + (double)dg2_w[o*128+i]
                          + 0.05*((double)dg1_w[o*128+64+i] + (double)dg2_w[o*128+64+i]);
                s += (double)dend_w[o2*64+o]*m0;
            }
        }
        W[ODEALL+id] = s;
    }
    for (int o2=tid; o2<32; o2+=nthr){
        double s = (double)dend_b[o2];
        for (int o=0;o<64;o++) s += (double)dend_w[o2*64+o]*((double)dg1_b[o]+(double)dg2_b[o]);
        W[ODEB+o2] = s;
        double wc = 0.0;
        for (int o3=0;o3<16;o3++) wc += (double)w_end[o3]*(double)dout_w[o3*32+o2];
        W[OWC+o2] = wc;
    }
    if (tid==0){
        double bc = (double)b_end[0];
        for (int o3=0;o3<16;o3++) bc += (double)w_end[o3]*(double)dout_b[o3];
        W[OBC] = bc;
    }
}

__global__ void k_emb(const int* __restrict__ idxp,
                      const float* __restrict__ emb1, const float* __restrict__ emb2,
                      const float* __restrict__ l1w, const float* __restrict__ l1b,
                      const float* __restrict__ l2w, const float* __restrict__ l2b,
                      double* __restrict__ n1, double* __restrict__ n2)
{
    int id = blockIdx.x*blockDim.x + threadIdx.x;   // 65536
    int i = id>>6, d = id&63;
    int ii = idxp[i];
    double a1 = (double)l1b[d], a2 = (double)l2b[d];
    for (int k=0;k<64;k++){
        a1 += (double)emb1[ii*64+k]*(double)l1w[d*64+k];
        a2 += (double)emb2[ii*64+k]*(double)l2w[d*64+k];
    }
    n1[id] = tanh(3.0*a1);
    n2[id] = tanh(3.0*a2);
}

__global__ __launch_bounds__(64) void k_topk(
    const double* __restrict__ n1, const double* __restrict__ n2,
    int* __restrict__ topc, double* __restrict__ topv,
    double* __restrict__ rs1, double* __restrict__ colsum)
{
    __shared__ double arow[NN];
    __shared__ double sn1[64], sn2[64];
    int i = blockIdx.x, lane = threadIdx.x;
    sn1[lane] = n1[i*64+lane];
    sn2[lane] = n2[i*64+lane];
    __syncthreads();
    for (int jb=0;jb<16;jb++){
        int j = jb*64 + lane;
        const double* p2 = n2 + j*64;
        const double* p1 = n1 + j*64;
        double d1v=0.0, d2v=0.0;
        for (int d=0;d<64;d++){ d1v += sn1[d]*p2[d]; d2v += sn2[d]*p1[d]; }
        double a = tanh(3.0*(d1v - d2v));
        arow[j] = a>0.0 ? a : 0.0;
    }
    __syncthreads();
    double rsum = 0.0;
    for (int r=0;r<TOPK;r++){
        double bv = -2.0; int bj = 1<<30;
        for (int jb=0;jb<16;jb++){
            int j = jb*64+lane;
            double v = arow[j];
            if (v>bv || (v==bv && j<bj)){ bv=v; bj=j; }
        }
        for (int off=32; off>=1; off>>=1){
            double ov = __shfl_xor(bv, off, 64);
            int    oj = __shfl_xor(bj, off, 64);
            if (ov>bv || (ov==bv && oj<bj)){ bv=ov; bj=oj; }
        }
        if (lane == (bj & 63)) arow[bj] = -2.0;
        if (lane == 0){
            topc[i*TOPK+r] = bj;
            topv[i*TOPK+r] = bv;
            if (bv > 0.0) atomicAdd(&colsum[bj], bv);
        }
        rsum += (bv > 0.0 ? bv : 0.0);
        __syncthreads();
    }
    if (lane == 0) rs1[i] = 1.0 + rsum;
}

__global__ void k_csc(const int* __restrict__ topc, const double* __restrict__ topv,
                      const double* __restrict__ rs1,
                      int* __restrict__ ccount, int* __restrict__ cidx, double* __restrict__ cw)
{
    int w = blockIdx.x*blockDim.x + threadIdx.x;
    if (w >= NN) return;
    double rv = rs1[w];
    for (int r=0;r<TOPK;r++){
        double v = topv[w*TOPK+r];
        if (v > 0.0){
            int col = topc[w*TOPK+r];
            int pos = atomicAdd(&ccount[col], 1);
            cidx[(long)col*NN+pos] = w;
            cw  [(long)col*NN+pos] = v / rv;
        }
    }
}

// pad each column's edge list to a multiple of 4 with zero-weight edges
__global__ void k_pad(int* __restrict__ ccount, int* __restrict__ cidx, double* __restrict__ cw)
{
    int col = blockIdx.x*blockDim.x + threadIdx.x;
    if (col >= NN) return;
    int cnt = ccount[col];
    int padded = (cnt + 3) & ~3;
    for (int e = cnt; e < padded; e++){
        cidx[(long)col*NN + e] = 0;
        cw  [(long)col*NN + e] = 0.0;
    }
    ccount[col] = padded;
}

__global__ void k_post1(const double* __restrict__ colsum, const double* __restrict__ rs1,
                        double* __restrict__ rs2, double* __restrict__ d1, double* __restrict__ d2)
{
    int v = blockIdx.x*blockDim.x + threadIdx.x;
    if (v >= NN) return;
    double r2 = 1.0 + colsum[v];
    rs2[v] = r2;
    d2[v] = 1.0/r2;
    d1[v] = 1.0/rs1[v];
}

__global__ void k_post2(const int* __restrict__ topc, const double* __restrict__ topv,
                        const double* __restrict__ rs2, double* __restrict__ ew2)
{
    int e = blockIdx.x*blockDim.x + threadIdx.x;
    if (e >= NN*TOPK) return;
    double v = topv[e];
    ew2[e] = (v > 0.0) ? v / rs2[topc[e]] : 0.0;
}

// x[B,T,N] fp32 -> xT[B,N,T] fp32
__global__ __launch_bounds__(256) void k_xT(const float* __restrict__ x, float* __restrict__ xT)
{
    __shared__ float tile[32][33];
    int b = blockIdx.z, t0 = blockIdx.x*32, n0 = blockIdx.y*32;
    int tx = threadIdx.x, ty = threadIdx.y;
    const float* xb = x + (long)b*NTP;
    for (int r=0;r<4;r++){
        int tl = ty + 8*r;
        tile[tl][tx] = xb[(long)(t0+tl)*NN + n0 + tx];
    }
    __syncthreads();
    float* ob = xT + (long)b*NTP;
    for (int r=0;r<4;r++){
        int nl = ty + 8*r;
        ob[(long)(n0+nl)*TTL + t0 + tx] = tile[tx][nl];
    }
}

// ============ pipeline kernels (planes [ch][v][t]) ============

// encoder gate (collapsed taps): x -> eg, pointwise, no gather
__global__ __launch_bounds__(256) void k_enc_gate(const float* __restrict__ xT,
    double* __restrict__ eg, const double* __restrict__ Wt, long S, int b0)
{
    int c = blockIdx.y;
    long p = (long)blockIdx.x*256 + threadIdx.x;
    int t = (int)(p & (TTL-1));
    double ft[3], fc[3], gt[3], gcc[3];
    #pragma unroll
    for (int k=0;k<3;k++){
        ft[k]=Wt[OEGTF_T+c*3+k]; fc[k]=Wt[OEGTF_C+c*3+k];
        gt[k]=Wt[OEGTG_T+c*3+k]; gcc[k]=Wt[OEGTG_C+c*3+k];
    }
    double fb = Wt[OEGTF_B+c], gb = Wt[OEGTG_B+c];
    const float* xp = xT + (long)b0*NTP + p;
    double xc = (double)xp[0];
    double atf = fb + ft[1]*xc + fc[1];
    double atg = gb + gt[1]*xc + gcc[1];
    if (t>0){ double xl = (double)xp[-1]; atf += ft[0]*xl + fc[0]; atg += gt[0]*xl + gcc[0]; }
    if (t<TTL-1){ double xr = (double)xp[1]; atf += ft[2]*xr + fc[2]; atg += gt[2]*xr + gcc[2]; }
    eg[(long)c*S + p] = tanh(atf)/(1.0+exp(-atg));
}

// generic graph gather, global-source form: block = 128 t-lanes, w uniform loop
// -> metadata via scalar loads, source reads coalesced from L2. 4-way MLP streams.
// y = dir*nch + ch; src plane = srcIsY ? y : ch.
__global__ __launch_bounds__(128) void k_gather(const double* __restrict__ src,
    double* __restrict__ q1, double* __restrict__ q2,
    const int* __restrict__ cc, const int* __restrict__ ci_, const double* __restrict__ cv_,
    const int* __restrict__ tc_, const double* __restrict__ e2_,
    const double* __restrict__ d1, const double* __restrict__ d2,
    long S, int nch, int srcIsY)
{
    int t = threadIdx.x;
    int y = blockIdx.y;
    int dir = (y >= nch) ? 1 : 0;
    int ch = y - dir*nch;
    int cb = blockIdx.z;
    int srcPlane = srcIsY ? y : ch;
    const double* sp = src + (long)srcPlane*S + (long)cb*NTP;
    double* dst = (dir ? q2 : q1) + (long)ch*S + (long)cb*NTP;
    int w0 = blockIdx.x * 8;
    for (int wi=0; wi<8; wi++){
        int w = w0 + wi;
        double g0 = sp[w*TTL + t];
        double a0, a1=0.0, a2=0.0, a3=0.0;
        if (dir == 0){
            a0 = g0 * d1[w];
            int cnt = cc[w];               // padded to multiple of 4
            const int* ci = ci_ + (long)w*NN;
            const double* cv = cv_ + (long)w*NN;
            for (int e=0; e<cnt; e+=4){
                a0 += cv[e]  *sp[ci[e]  *TTL + t];
                a1 += cv[e+1]*sp[ci[e+1]*TTL + t];
                a2 += cv[e+2]*sp[ci[e+2]*TTL + t];
                a3 += cv[e+3]*sp[ci[e+3]*TTL + t];
            }
        } else {
            a0 = g0 * d2[w];
            const int* tc = tc_ + w*TOPK;
            const double* e2 = e2_ + w*TOPK;
            #pragma unroll
            for (int r=0; r<28; r+=4){
                a0 += e2[r]  *sp[tc[r]  *TTL + t];
                a1 += e2[r+1]*sp[tc[r+1]*TTL + t];
                a2 += e2[r+2]*sp[tc[r+2]*TTL + t];
                a3 += e2[r+3]*sp[tc[r+3]*TTL + t];
            }
            a0 += e2[28]*sp[tc[28]*TTL + t];
            a1 += e2[29]*sp[tc[29]*TTL + t];
        }
        dst[w*TTL + t] = (a0+a1)+(a2+a3);
    }
}

// encoder tail: fused (mix.end) -> relu -> e32 planes (eout folded into dec_gate)
__global__ __launch_bounds__(256) void k_enc_tail(const double* __restrict__ Bp,
    double* __restrict__ E32, const double* __restrict__ Wt, long S)
{
    long p = (long)blockIdx.x*256 + threadIdx.x;
    double e[32];
    #pragma unroll
    for (int o2=0;o2<32;o2++) e[o2] = Wt[OEEB+o2];
    for (int i=0;i<16;i++){
        double a = Bp[(long)i*S+p], b = Bp[(long)(16+i)*S+p], c = Bp[(long)(32+i)*S+p];
        const double* w0 = Wt+OEE0+i*32;
        const double* w1 = Wt+OEE1+i*32;
        const double* w2 = Wt+OEE2+i*32;
        #pragma unroll
        for (int o2=0;o2<32;o2++) e[o2] += w0[o2]*a + w1[o2]*b + w2[o2]*c;
    }
    #pragma unroll
    for (int o2=0;o2<32;o2++){
        double v = e[o2];
        E32[(long)o2*S+p] = v>0.0 ? v : 0.0;
    }
}

// decoder gated tconv with eout folded in: K=32 e-channels x 3 taps.
// block = 2 v-strips x 128 t, XCD-aware oc map.
__global__ __launch_bounds__(256) void k_dec_gate(const double* __restrict__ E32,
    double* __restrict__ g, const double* __restrict__ Wt, long S)
{
    int bx = blockIdx.x;
    int oc = (bx >> 3) & 3;
    long vpair = (long)(bx >> 5)*8 + (bx & 7);
    int tid = threadIdx.x;
    int t = tid & 127, vv = tid >> 7;
    long vstrip = vpair*2 + vv;
    long pos = vstrip*TTL + t;
    bool hasL = (t>0), hasR = (t<TTL-1);
    double af[16], ag[16];
    #pragma unroll
    for (int o=0;o<16;o++){
        double bf = Wt[ODTF_B+oc*16+o] + Wt[OCF+oc*48+o*3+1];
        double bg = Wt[ODTG_B+oc*16+o] + Wt[OCG+oc*48+o*3+1];
        if (hasL){ bf += Wt[OCF+oc*48+o*3];   bg += Wt[OCG+oc*48+o*3]; }
        if (hasR){ bf += Wt[OCF+oc*48+o*3+2]; bg += Wt[OCG+oc*48+o*3+2]; }
        af[o]=bf; ag[o]=bg;
    }
    #pragma unroll 1
    for (int j=0;j<32;j++){
        const double* xp = E32 + (long)j*S + pos;
        double xc = xp[0];
        double xl = hasL ? xp[-1] : 0.0;
        double xr = hasR ? xp[1]  : 0.0;
        const double* wfg = Wt + ODTW2 + (long)(oc*32+j)*96;
        #pragma unroll
        for (int o=0;o<16;o++){
            af[o] += wfg[o*3]*xl + wfg[o*3+1]*xc + wfg[o*3+2]*xr;
            ag[o] += wfg[48+o*3]*xl + wfg[48+o*3+1]*xc + wfg[48+o*3+2]*xr;
        }
    }
    #pragma unroll
    for (int o=0;o<16;o++){
        g[(long)(oc*16+o)*S + pos] = tanh(af[o])/(1.0+exp(-ag[o]));
    }
}

// decoder fused-mix pointwise conv, merged 2-pass: jc0 -> P1+P2, jc1 -> P0
__global__ __launch_bounds__(256) void k_dec_conv(const double* __restrict__ g,
    double* __restrict__ Cp, double* __restrict__ P0p,
    const double* __restrict__ Wt, long S)
{
    long p = (long)blockIdx.x*256 + threadIdx.x;
    int jc = blockIdx.y;
    if (jc == 0){
        double a1[32], a2[32];
        #pragma unroll
        for (int jj=0;jj<32;jj++){ a1[jj]=0.0; a2[jj]=0.0; }
        #pragma unroll 1
        for (int i=0;i<64;i++){
            double gv = g[(long)i*S+p];
            const double* wr = Wt + ODEALL + i*96;
            #pragma unroll
            for (int jj=0;jj<32;jj++){ a1[jj] += wr[jj]*gv; a2[jj] += wr[32+jj]*gv; }
        }
        #pragma unroll
        for (int jj=0;jj<32;jj++){
            Cp[(long)jj*S+p] = a1[jj];
            Cp[(long)(32+jj)*S+p] = a2[jj];
        }
    } else {
        double a0[32];
        #pragma unroll
        for (int jj=0;jj<32;jj++) a0[jj] = Wt[ODEB+jj];
        #pragma unroll 1
        for (int i=0;i<64;i++){
            double gv = g[(long)i*S+p];
            const double* wr = Wt + ODEALL + i*96 + 64;
            #pragma unroll
            for (int jj=0;jj<32;jj++) a0[jj] += wr[jj]*gv;
        }
        #pragma unroll
        for (int jj=0;jj<32;jj++) P0p[(long)jj*S+p] = a0[jj];
    }
}

// decoder tail: e = P0 + Q1 + Q2 -> relu -> fused (dout.w_end) dot -> fp32 [B,T,N]
__global__ __launch_bounds__(256) void k_dec_tail(const double* __restrict__ P0,
    const double* __restrict__ Q1, const double* __restrict__ Q2,
    const double* __restrict__ Wt, float* __restrict__ out, long S, int b0)
{
    long p = (long)blockIdx.x*256 + threadIdx.x;
    double res = Wt[OBC];
    #pragma unroll 8
    for (int o2=0;o2<32;o2++){
        double e = P0[(long)o2*S+p] + Q1[(long)o2*S+p] + Q2[(long)o2*S+p];
        e = e>0.0 ? e : 0.0;
        res += Wt[OWC+o2]*e;
    }
    int cb = (int)(p >> 17);
    long r = p & (NTP-1);
    int v = (int)(r >> 7), t = (int)(r & (TTL-1));
    out[((long)(b0+cb)*TTL + t)*NN + v] = (float)res;
}

// ============ launch ============

extern "C" void kernel_launch(void* const* d_in, const int* in_sizes, int n_in,
                              void* d_out, int out_size, void* d_ws, size_t ws_size,
                              hipStream_t stream)
{
    const float* x      = (const float*)d_in[0];
    const int*   idx    = (const int*)  d_in[1];
    const float* emb1   = (const float*)d_in[2];
    const float* emb2   = (const float*)d_in[3];
    const float* lin1_w = (const float*)d_in[4];
    const float* lin1_b = (const float*)d_in[5];
    const float* lin2_w = (const float*)d_in[6];
    const float* lin2_b = (const float*)d_in[7];
    const float* w_start= (const float*)d_in[8];
    const float* b_start= (const float*)d_in[9];
    const float* etf_w  = (const float*)d_in[10];
    const float* etf_b  = (const float*)d_in[11];
    const float* etg_w  = (const float*)d_in[12];
    const float* etg_b  = (const float*)d_in[13];
    const float* eg1_w  = (const float*)d_in[14];
    const float* eg1_b  = (const float*)d_in[15];
    const float* eg2_w  = (const float*)d_in[16];
    const float* eg2_b  = (const float*)d_in[17];
    const float* eend_w = (const float*)d_in[18];
    const float* eend_b = (const float*)d_in[19];
    const float* eout_w = (const float*)d_in[20];
    const float* eout_b = (const float*)d_in[21];
    const float* dtf_w  = (const float*)d_in[22];
    const float* dtf_b  = (const float*)d_in[23];
    const float* dtg_w  = (const float*)d_in[24];
    const float* dtg_b  = (const float*)d_in[25];
    const float* dg1_w  = (const float*)d_in[26];
    const float* dg1_b  = (const float*)d_in[27];
    const float* dg2_w  = (const float*)d_in[28];
    const float* dg2_b  = (const float*)d_in[29];
    const float* dend_w = (const float*)d_in[30];
    const float* dend_b = (const float*)d_in[31];
    const float* dout_w = (const float*)d_in[32];
    const float* dout_b = (const float*)d_in[33];
    const float* w_end  = (const float*)d_in[34];
    const float* b_end  = (const float*)d_in[35];
    float* out = (float*)d_out;

    char* basep = (char*)d_ws;
    size_t cur = 0;
    auto alloc = [&](size_t bytes)->void* {
        void* p = basep + cur;
        cur = (cur + bytes + 511) & ~(size_t)511;
        return p;
    };
    double* W     = (double*)alloc(WTOT*sizeof(double));
    double* n1    = (double*)alloc(65536*sizeof(double));
    double* n2    = (double*)alloc(65536*sizeof(double));
    double* topv  = (double*)alloc((size_t)NN*TOPK*sizeof(double));
    int*    topc  = (int*)   alloc((size_t)NN*TOPK*sizeof(int));
    double* rs1   = (double*)alloc(NN*sizeof(double));
    double* rs2   = (double*)alloc(NN*sizeof(double));
    double* colsum= (double*)alloc(NN*sizeof(double));
    double* d1a   = (double*)alloc(NN*sizeof(double));
    double* d2a   = (double*)alloc(NN*sizeof(double));
    double* ew2   = (double*)alloc((size_t)NN*TOPK*sizeof(double));
    int*    ccount= (int*)   alloc(NN*sizeof(int));
    int*    cidx  = (int*)   alloc((size_t)NN*NN*sizeof(int));
    double* cw    = (double*)alloc((size_t)NN*NN*sizeof(double));
    float*  xT    = (float*) alloc((size_t)16*NTP*sizeof(float));

    // plane arena: A(64) + B(48) + C(64) channel planes of CB*NTP doubles
    size_t perb = (size_t)176 * NTP * sizeof(double);
    int CB = 1;
    for (int c = 16; c >= 1; c >>= 1){
        if (cur + perb*(size_t)c <= ws_size){ CB = c; break; }
    }
    long S = (long)CB * NTP;
    double* A = (double*)alloc((size_t)64*S*sizeof(double));
    double* B = (double*)alloc((size_t)48*S*sizeof(double));
    double* C = (double*)alloc((size_t)64*S*sizeof(double));

    (void)hipMemsetAsync(colsum, 0, NN*sizeof(double), stream);
    (void)hipMemsetAsync(ccount, 0, NN*sizeof(int), stream);

    k_prep_weights<<<32,256,0,stream>>>(
        w_start,b_start, etf_w,etf_b, etg_w,etg_b, eg1_w,eg1_b, eg2_w,eg2_b,
        eend_w,eend_b, eout_w,eout_b, dtf_w,dtf_b, dtg_w,dtg_b, dg1_w,dg1_b,
        dg2_w,dg2_b, dend_w,dend_b, dout_w,dout_b, w_end,b_end, W);
    k_emb<<<256,256,0,stream>>>(idx, emb1, emb2, lin1_w, lin1_b, lin2_w, lin2_b, n1, n2);
    k_topk<<<NN,64,0,stream>>>(n1, n2, topc, topv, rs1, colsum);
    k_csc<<<4,256,0,stream>>>(topc, topv, rs1, ccount, cidx, cw);
    k_pad<<<4,256,0,stream>>>(ccount, cidx, cw);
    k_post1<<<4,256,0,stream>>>(colsum, rs1, rs2, d1a, d2a);
    k_post2<<<(NN*TOPK+255)/256,256,0,stream>>>(topc, topv, rs2, ew2);
    k_xT<<<dim3(4,32,16),dim3(32,8),0,stream>>>(x, xT);

    int nch = 16 / CB;
    for (int ch=0; ch<nch; ch++){
        int b0 = ch*CB;
        // encoder gate: x -> eg (B[0:16])
        k_enc_gate<<<dim3(512*CB,16),256,0,stream>>>(xT, B, W, S, b0);
        // encoder gather: eg -> es1 (B[16:32]), es2 (B[32:48])
        k_gather<<<dim3(128,32,CB),128,0,stream>>>(B, B+(long)16*S, B+(long)32*S,
            ccount,cidx,cw, topc,ew2, d1a,d2a, S, 16, 0);
        // encoder tail: B[0:48] -> e32 (A[0:32])
        k_enc_tail<<<512*CB,256,0,stream>>>(B, A, W, S);
        // decoder gate (eout folded): e32(A) -> g (C[0:64])
        k_dec_gate<<<2048*CB,256,0,stream>>>(A, C, W, S);
        // decoder fused-mix conv: g(C) -> P1,P2 (A[0:64]), P0 (B[0:32])
        k_dec_conv<<<dim3(512*CB,2),256,0,stream>>>(C, A, B, W, S);
        // decoder gather: A(P1,P2) -> Q1 (C[0:32]), Q2 (C[32:64])
        k_gather<<<dim3(128,64,CB),128,0,stream>>>(A, C, C+(long)32*S,
            ccount,cidx,cw, topc,ew2, d1a,d2a, S, 32, 1);
        // decoder tail -> out
        k_dec_tail<<<512*CB,256,0,stream>>>(B, C, C+(long)32*S, W, out, S, b0);
    }
    (void)in_sizes; (void)n_in; (void)out_size;
}

// Round 18
// 7455.300 us; speedup vs baseline: 1.3805x; 1.3805x over previous
//
#include <hip/hip_runtime.h>
#include <math.h>

#define NN   1024
#define TTL  128
#define NTP  131072   // NN*TTL
#define TOPK 30

// ---- fp64 weight region offsets (in doubles) ----
#define OEGTF_T 0
#define OEGTF_C 48
#define OEGTF_B 96
#define OEGTG_T 112
#define OEGTG_C 160
#define OEGTG_B 208
#define OEE0    224
#define OEE1    736
#define OEE2    1248
#define OEEB    1760
#define OEOUT_W 1792
#define OEOUT_B 3840
#define ODTF_B  16192
#define ODTG_B  28544
#define ODEB    34752
#define OWC     34784
#define OBC     34816
#define ODEALL  59456   // [i][96]: [0:32]=E1, [32:64]=E2, [64:96]=E0 (6144)
#define ODTW2   65600   // folded (tconv.eout): [oc][j=32][96] f taps 0..47, g taps 48..95 (12288)
#define OCF     77888   // f per-tap consts [oc][o][k] (192)
#define OCG     78080   // g per-tap consts (192)
#define WTOT    78272

// ============ setup kernels ============

__global__ void k_prep_weights(
    const float* __restrict__ w_start, const float* __restrict__ b_start,
    const float* __restrict__ etf_w, const float* __restrict__ etf_b,
    const float* __restrict__ etg_w, const float* __restrict__ etg_b,
    const float* __restrict__ eg1_w, const float* __restrict__ eg1_b,
    const float* __restrict__ eg2_w, const float* __restrict__ eg2_b,
    const float* __restrict__ eend_w, const float* __restrict__ eend_b,
    const float* __restrict__ eout_w, const float* __restrict__ eout_b,
    const float* __restrict__ dtf_w, const float* __restrict__ dtf_b,
    const float* __restrict__ dtg_w, const float* __restrict__ dtg_b,
    const float* __restrict__ dg1_w, const float* __restrict__ dg1_b,
    const float* __restrict__ dg2_w, const float* __restrict__ dg2_b,
    const float* __restrict__ dend_w, const float* __restrict__ dend_b,
    const float* __restrict__ dout_w, const float* __restrict__ dout_b,
    const float* __restrict__ w_end, const float* __restrict__ b_end,
    double* __restrict__ W)
{
    int tid = blockIdx.x*blockDim.x + threadIdx.x;
    int nthr = gridDim.x*blockDim.x;
    // encoder gate collapsed through w_start: tap[o][k] = sum_i w[o,i,k]*ws[i]
    for (int id=tid; id<96; id+=nthr){
        int which = id/48; int r = id%48; int o = r/3, k = r%3;
        const float* w = which ? etg_w : etf_w;
        double t=0.0, c=0.0;
        for (int i=0;i<16;i++){
            double wv = (double)w[(o*16+i)*3+k];
            t += wv*(double)w_start[i];
            c += wv*(double)b_start[i];
        }
        W[(which?OEGTG_T:OEGTF_T)+o*3+k] = t;
        W[(which?OEGTG_C:OEGTF_C)+o*3+k] = c;
    }
    for (int i=tid;i<16;i+=nthr){
        W[OEGTF_B+i] = (double)etf_b[i];
        W[OEGTG_B+i] = (double)etg_b[i];
    }
    // encoder fused (mix . end) matrices: Ee_k[i][o2] = sum_o eend_w[o2][o]*Mk[i][o]
    for (int id=tid; id<512; id+=nthr){
        int i = id>>5, o2 = id&31;
        double s0=0.0, s1=0.0, s2=0.0;
        for (int o=0;o<16;o++){
            double m0 = (double)eg1_w[o*32+i] + (double)eg2_w[o*32+i]
                      + 0.05*((double)eg1_w[o*32+16+i] + (double)eg2_w[o*32+16+i]);
            double m1 = 0.95*(double)eg1_w[o*32+16+i];
            double m2 = 0.95*(double)eg2_w[o*32+16+i];
            double ew = (double)eend_w[o2*16+o];
            s0 += ew*m0; s1 += ew*m1; s2 += ew*m2;
        }
        W[OEE0+i*32+o2]=s0; W[OEE1+i*32+o2]=s1; W[OEE2+i*32+o2]=s2;
    }
    for (int o2=tid; o2<32; o2+=nthr){
        double s = (double)eend_b[o2];
        for (int o=0;o<16;o++) s += (double)eend_w[o2*16+o]*((double)eg1_b[o]+(double)eg2_b[o]);
        W[OEEB+o2] = s;
    }
    for (int i=tid;i<64;i+=nthr){
        W[ODTF_B+i]=(double)dtf_b[i]; W[ODTG_B+i]=(double)dtg_b[i];
    }
    // folded decoder tconv weights: W'[oc][j][q], q<48: f (o*3+k), q>=48: g
    for (int id=tid; id<12288; id+=nthr){
        int oc = id/3072; int rem = id%3072; int j = rem/96; int q = rem%96;
        const float* w = (q<48) ? dtf_w : dtg_w;
        int q2 = (q<48) ? q : q-48;
        int o = q2/3, k = q2%3;
        double s = 0.0;
        for (int i=0;i<64;i++)
            s += (double)w[((oc*16+o)*64+i)*3+k]*(double)eout_w[i*32+j];
        W[ODTW2+id] = s;
    }
    // per-tap constants from eout_b
    for (int id=tid; id<384; id+=nthr){
        int which = id/192; int r = id%192;
        int oc = r/48; int q = r%48; int o = q/3, k = q%3;
        const float* w = which ? dtg_w : dtf_w;
        double s = 0.0;
        for (int i=0;i<64;i++)
            s += (double)w[((oc*16+o)*64+i)*3+k]*(double)eout_b[i];
        W[(which?OCG:OCF) + oc*48 + o*3 + k] = s;
    }
    // decoder fused (mix . end) matrices, combined layout [i][96]
    for (int id=tid; id<6144; id+=nthr){
        int i = id/96, j = id%96;
        double s = 0.0;
        if (j < 32){
            int o2 = j;
            for (int o=0;o<64;o++){
                double m1 = 0.95*(double)dg1_w[o*128+64+i];
                s += (double)dend_w[o2*64+o]*m1;
            }
        } else if (j < 64){
            int o2 = j-32;
            for (int o=0;o<64;o++){
                double m2 = 0.95*(double)dg2_w[o*128+64+i];
                s += (double)dend_w[o2*64+o]*m2;
            }
        } else {
            int o2 = j-64;
            for (int o=0;o<64;o++){
                double m0 = (double)dg1_w[o*128+i] + (double)dg2_w[o*128+i]
                          + 0.05*((double)dg1_w[o*128+64+i] + (double)dg2_w[o*128+64+i]);
                s += (double)dend_w[o2*64+o]*m0;
            }
        }
        W[ODEALL+id] = s;
    }
    for (int o2=tid; o2<32; o2+=nthr){
        double s = (double)dend_b[o2];
        for (int o=0;o<64;o++) s += (double)dend_w[o2*64+o]*((double)dg1_b[o]+(double)dg2_b[o]);
        W[ODEB+o2] = s;
        double wc = 0.0;
        for (int o3=0;o3<16;o3++) wc += (double)w_end[o3]*(double)dout_w[o3*32+o2];
        W[OWC+o2] = wc;
    }
    if (tid==0){
        double bc = (double)b_end[0];
        for (int o3=0;o3<16;o3++) bc += (double)w_end[o3]*(double)dout_b[o3];
        W[OBC] = bc;
    }
}

__global__ void k_emb(const int* __restrict__ idxp,
                      const float* __restrict__ emb1, const float* __restrict__ emb2,
                      const float* __restrict__ l1w, const float* __restrict__ l1b,
                      const float* __restrict__ l2w, const float* __restrict__ l2b,
                      double* __restrict__ n1, double* __restrict__ n2)
{
    int id = blockIdx.x*blockDim.x + threadIdx.x;   // 65536
    int i = id>>6, d = id&63;
    int ii = idxp[i];
    double a1 = (double)l1b[d], a2 = (double)l2b[d];
    for (int k=0;k<64;k++){
        a1 += (double)emb1[ii*64+k]*(double)l1w[d*64+k];
        a2 += (double)emb2[ii*64+k]*(double)l2w[d*64+k];
    }
    n1[id] = tanh(3.0*a1);
    n2[id] = tanh(3.0*a2);
}

__global__ __launch_bounds__(64) void k_topk(
    const double* __restrict__ n1, const double* __restrict__ n2,
    int* __restrict__ topc, double* __restrict__ topv,
    double* __restrict__ rs1, double* __restrict__ colsum)
{
    __shared__ double arow[NN];
    __shared__ double sn1[64], sn2[64];
    int i = blockIdx.x, lane = threadIdx.x;
    sn1[lane] = n1[i*64+lane];
    sn2[lane] = n2[i*64+lane];
    __syncthreads();
    for (int jb=0;jb<16;jb++){
        int j = jb*64 + lane;
        const double* p2 = n2 + j*64;
        const double* p1 = n1 + j*64;
        double d1v=0.0, d2v=0.0;
        for (int d=0;d<64;d++){ d1v += sn1[d]*p2[d]; d2v += sn2[d]*p1[d]; }
        double a = tanh(3.0*(d1v - d2v));
        arow[j] = a>0.0 ? a : 0.0;
    }
    __syncthreads();
    double rsum = 0.0;
    for (int r=0;r<TOPK;r++){
        double bv = -2.0; int bj = 1<<30;
        for (int jb=0;jb<16;jb++){
            int j = jb*64+lane;
            double v = arow[j];
            if (v>bv || (v==bv && j<bj)){ bv=v; bj=j; }
        }
        for (int off=32; off>=1; off>>=1){
            double ov = __shfl_xor(bv, off, 64);
            int    oj = __shfl_xor(bj, off, 64);
            if (ov>bv || (ov==bv && oj<bj)){ bv=ov; bj=oj; }
        }
        if (lane == (bj & 63)) arow[bj] = -2.0;
        if (lane == 0){
            topc[i*TOPK+r] = bj;
            topv[i*TOPK+r] = bv;
            if (bv > 0.0) atomicAdd(&colsum[bj], bv);
        }
        rsum += (bv > 0.0 ? bv : 0.0);
        __syncthreads();
    }
    if (lane == 0) rs1[i] = 1.0 + rsum;
}

__global__ void k_csc(const int* __restrict__ topc, const double* __restrict__ topv,
                      const double* __restrict__ rs1,
                      int* __restrict__ ccount, int* __restrict__ cidx, double* __restrict__ cw)
{
    int w = blockIdx.x*blockDim.x + threadIdx.x;
    if (w >= NN) return;
    double rv = rs1[w];
    for (int r=0;r<TOPK;r++){
        double v = topv[w*TOPK+r];
        if (v > 0.0){
            int col = topc[w*TOPK+r];
            int pos = atomicAdd(&ccount[col], 1);
            cidx[(long)col*NN+pos] = w;
            cw  [(long)col*NN+pos] = v / rv;
        }
    }
}

// pad each column's edge list to a multiple of 8 with zero-weight edges
// (appended after the real edges; 0.0 * x contributes exact 0 -> bit-identical)
__global__ void k_pad(int* __restrict__ ccount, int* __restrict__ cidx, double* __restrict__ cw)
{
    int col = blockIdx.x*blockDim.x + threadIdx.x;
    if (col >= NN) return;
    int cnt = ccount[col];
    int padded = (cnt + 7) & ~7;
    for (int e = cnt; e < padded; e++){
        cidx[(long)col*NN + e] = 0;
        cw  [(long)col*NN + e] = 0.0;
    }
    ccount[col] = padded;
}

__global__ void k_post1(const double* __restrict__ colsum, const double* __restrict__ rs1,
                        double* __restrict__ rs2, double* __restrict__ d1, double* __restrict__ d2)
{
    int v = blockIdx.x*blockDim.x + threadIdx.x;
    if (v >= NN) return;
    double r2 = 1.0 + colsum[v];
    rs2[v] = r2;
    d2[v] = 1.0/r2;
    d1[v] = 1.0/rs1[v];
}

__global__ void k_post2(const int* __restrict__ topc, const double* __restrict__ topv,
                        const double* __restrict__ rs2, double* __restrict__ ew2)
{
    int e = blockIdx.x*blockDim.x + threadIdx.x;
    if (e >= NN*TOPK) return;
    double v = topv[e];
    ew2[e] = (v > 0.0) ? v / rs2[topc[e]] : 0.0;
}

// x[B,T,N] fp32 -> xT[B,N,T] fp32
__global__ __launch_bounds__(256) void k_xT(const float* __restrict__ x, float* __restrict__ xT)
{
    __shared__ float tile[32][33];
    int b = blockIdx.z, t0 = blockIdx.x*32, n0 = blockIdx.y*32;
    int tx = threadIdx.x, ty = threadIdx.y;
    const float* xb = x + (long)b*NTP;
    for (int r=0;r<4;r++){
        int tl = ty + 8*r;
        tile[tl][tx] = xb[(long)(t0+tl)*NN + n0 + tx];
    }
    __syncthreads();
    float* ob = xT + (long)b*NTP;
    for (int r=0;r<4;r++){
        int nl = ty + 8*r;
        ob[(long)(n0+nl)*TTL + t0 + tx] = tile[tx][nl];
    }
}

// ============ pipeline kernels (planes [ch][v][t]) ============

// encoder: gate (collapsed taps) fused into graph staging; t-tile=4, stride-6 LDS,
// double2 gather, 8-wide batched edge loads (padded lists) for MLP
__global__ __launch_bounds__(256) void k_enc_gg(const float* __restrict__ xT,
    double* __restrict__ eg, double* __restrict__ es1, double* __restrict__ es2,
    const double* __restrict__ Wt,
    const int* __restrict__ ccount, const int* __restrict__ cidx, const double* __restrict__ cw,
    const int* __restrict__ topc, const double* __restrict__ ew2,
    const double* __restrict__ d1, const double* __restrict__ d2,
    long S, int b0)
{
    __shared__ double ldsg[NN*6];   // 48 KB, stride 6 (pad 2)
    int tid = threadIdx.x, c = blockIdx.y, cb = blockIdx.z, t0 = blockIdx.x*4;
    double ft[3], fc[3], gt[3], gcc[3];
    #pragma unroll
    for (int k=0;k<3;k++){
        ft[k]=Wt[OEGTF_T+c*3+k]; fc[k]=Wt[OEGTF_C+c*3+k];
        gt[k]=Wt[OEGTG_T+c*3+k]; gcc[k]=Wt[OEGTG_C+c*3+k];
    }
    double fb = Wt[OEGTF_B+c], gb = Wt[OEGTG_B+c];
    const float* xb = xT + (long)(b0+cb)*NTP;
    long base = (long)c*S + (long)cb*NTP;
    for (int k=0;k<16;k++){
        int idx = k*256 + tid;
        int v = idx>>2, tl = idx&3, t = t0+tl;
        const float* xp = xb + (long)v*TTL + t;
        double xc = (double)xp[0];
        double atf = fb + ft[1]*xc + fc[1];
        double atg = gb + gt[1]*xc + gcc[1];
        if (t>0){ double xl = (double)xp[-1]; atf += ft[0]*xl + fc[0]; atg += gt[0]*xl + gcc[0]; }
        if (t<TTL-1){ double xr = (double)xp[1]; atf += ft[2]*xr + fc[2]; atg += gt[2]*xr + gcc[2]; }
        double gv = tanh(atf)/(1.0+exp(-atg));
        ldsg[v*6+tl] = gv;
        eg[base + (long)v*TTL + t] = gv;
    }
    __syncthreads();
    int wi = tid>>1, tl2 = tid&1;
    for (int wb=0;wb<8;wb++){
        int w = wb*128 + wi;
        double2 gc2 = *(const double2*)&ldsg[w*6 + 2*tl2];
        long p = base + (long)w*TTL + t0 + 2*tl2;
        double dv = d1[w];
        double a1x = gc2.x*dv, a1y = gc2.y*dv;
        int cnt = ccount[w];               // padded to multiple of 8
        const int* ci = cidx + (long)w*NN;
        const double* cv = cw + (long)w*NN;
        for (int e0=0; e0<cnt; e0+=8){
            #pragma unroll
            for (int k=0;k<8;k++){
                double wt_ = cv[e0+k];
                double2 s = *(const double2*)&ldsg[ci[e0+k]*6 + 2*tl2];
                a1x += wt_*s.x; a1y += wt_*s.y;
            }
        }
        double2 r1; r1.x=a1x; r1.y=a1y;
        *(double2*)&es1[p] = r1;
        double d2v = d2[w];
        double a2x = gc2.x*d2v, a2y = gc2.y*d2v;
        const int* tc = topc + w*TOPK;
        const double* e2 = ew2 + w*TOPK;
        for (int r0=0;r0<TOPK;r0+=6){
            #pragma unroll
            for (int k=0;k<6;k++){
                double wv = e2[r0+k];
                double2 s = *(const double2*)&ldsg[tc[r0+k]*6 + 2*tl2];
                a2x += wv*s.x; a2y += wv*s.y;   // wv==0 contributes exact 0
            }
        }
        double2 r2v; r2v.x=a2x; r2v.y=a2y;
        *(double2*)&es2[p] = r2v;
    }
}

// encoder tail: fused (mix.end) -> relu -> e32 planes (eout folded into dec_gate)
__global__ __launch_bounds__(256) void k_enc_tail(const double* __restrict__ Bp,
    double* __restrict__ E32, const double* __restrict__ Wt, long S)
{
    long p = (long)blockIdx.x*256 + threadIdx.x;
    double e[32];
    #pragma unroll
    for (int o2=0;o2<32;o2++) e[o2] = Wt[OEEB+o2];
    for (int i=0;i<16;i++){
        double a = Bp[(long)i*S+p], b = Bp[(long)(16+i)*S+p], c = Bp[(long)(32+i)*S+p];
        const double* w0 = Wt+OEE0+i*32;
        const double* w1 = Wt+OEE1+i*32;
        const double* w2 = Wt+OEE2+i*32;
        #pragma unroll
        for (int o2=0;o2<32;o2++) e[o2] += w0[o2]*a + w1[o2]*b + w2[o2]*c;
    }
    #pragma unroll
    for (int o2=0;o2<32;o2++){
        double v = e[o2];
        E32[(long)o2*S+p] = v>0.0 ? v : 0.0;
    }
}

// decoder gated tconv with eout folded in: K=32 e-channels x 3 taps.
// block = 2 v-strips x 128 t, XCD-aware oc map.
__global__ __launch_bounds__(256) void k_dec_gate(const double* __restrict__ E32,
    double* __restrict__ g, const double* __restrict__ Wt, long S)
{
    int bx = blockIdx.x;
    int oc = (bx >> 3) & 3;
    long vpair = (long)(bx >> 5)*8 + (bx & 7);
    int tid = threadIdx.x;
    int t = tid & 127, vv = tid >> 7;
    long vstrip = vpair*2 + vv;
    long pos = vstrip*TTL + t;
    bool hasL = (t>0), hasR = (t<TTL-1);
    double af[16], ag[16];
    #pragma unroll
    for (int o=0;o<16;o++){
        double bf = Wt[ODTF_B+oc*16+o] + Wt[OCF+oc*48+o*3+1];
        double bg = Wt[ODTG_B+oc*16+o] + Wt[OCG+oc*48+o*3+1];
        if (hasL){ bf += Wt[OCF+oc*48+o*3];   bg += Wt[OCG+oc*48+o*3]; }
        if (hasR){ bf += Wt[OCF+oc*48+o*3+2]; bg += Wt[OCG+oc*48+o*3+2]; }
        af[o]=bf; ag[o]=bg;
    }
    #pragma unroll 1
    for (int j=0;j<32;j++){
        const double* xp = E32 + (long)j*S + pos;
        double xc = xp[0];
        double xl = hasL ? xp[-1] : 0.0;
        double xr = hasR ? xp[1]  : 0.0;
        const double* wfg = Wt + ODTW2 + (long)(oc*32+j)*96;
        #pragma unroll
        for (int o=0;o<16;o++){
            af[o] += wfg[o*3]*xl + wfg[o*3+1]*xc + wfg[o*3+2]*xr;
            ag[o] += wfg[48+o*3]*xl + wfg[48+o*3+1]*xc + wfg[48+o*3+2]*xr;
        }
    }
    #pragma unroll
    for (int o=0;o<16;o++){
        g[(long)(oc*16+o)*S + pos] = tanh(af[o])/(1.0+exp(-ag[o]));
    }
}

// decoder fused-mix pointwise conv, merged 2-pass: jc0 -> P1+P2 (one g read),
// jc1 -> P0. Weight rows uniform.
__global__ __launch_bounds__(256) void k_dec_conv(const double* __restrict__ g,
    double* __restrict__ Cp, double* __restrict__ P0p,
    const double* __restrict__ Wt, long S)
{
    long p = (long)blockIdx.x*256 + threadIdx.x;
    int jc = blockIdx.y;
    if (jc == 0){
        double a1[32], a2[32];
        #pragma unroll
        for (int jj=0;jj<32;jj++){ a1[jj]=0.0; a2[jj]=0.0; }
        #pragma unroll 1
        for (int i=0;i<64;i++){
            double gv = g[(long)i*S+p];
            const double* wr = Wt + ODEALL + i*96;
            #pragma unroll
            for (int jj=0;jj<32;jj++){ a1[jj] += wr[jj]*gv; a2[jj] += wr[32+jj]*gv; }
        }
        #pragma unroll
        for (int jj=0;jj<32;jj++){
            Cp[(long)jj*S+p] = a1[jj];
            Cp[(long)(32+jj)*S+p] = a2[jj];
        }
    } else {
        double a0[32];
        #pragma unroll
        for (int jj=0;jj<32;jj++) a0[jj] = Wt[ODEB+jj];
        #pragma unroll 1
        for (int i=0;i<64;i++){
            double gv = g[(long)i*S+p];
            const double* wr = Wt + ODEALL + i*96 + 64;
            #pragma unroll
            for (int jj=0;jj<32;jj++) a0[jj] += wr[jj]*gv;
        }
        #pragma unroll
        for (int jj=0;jj<32;jj++) P0p[(long)jj*S+p] = a0[jj];
    }
}

// decoder graph gather, BOTH dirs per block: stage P1[ch] -> dir-0 partials in
// registers, restage P2[ch] -> dir-1, write summed Q12 once. Batched edge loads.
__global__ __launch_bounds__(256) void k_graph32(const double* __restrict__ P1,
    const double* __restrict__ P2, double* __restrict__ Q12,
    const int* __restrict__ ccount, const int* __restrict__ cidx, const double* __restrict__ cw,
    const int* __restrict__ topc, const double* __restrict__ ew2,
    const double* __restrict__ d1, const double* __restrict__ d2, long S)
{
    __shared__ double lds[NN*6];   // 48 KB
    int tid = threadIdx.x;
    int ch = blockIdx.y;           // 0..31
    int cb = blockIdx.z;
    long base = (long)ch*S + (long)cb*NTP;
    int t0 = blockIdx.x*4;
    int wi = tid>>1, tl2 = tid&1;
    double r1x[8], r1y[8];
    // ---- dir 0: source P1[ch] ----
    {
        const double* src = P1 + base;
        for (int k=0;k<16;k++){
            int idx = k*256 + tid;
            int v = idx>>2, tl = idx&3;
            lds[v*6+tl] = src[(long)v*TTL + t0 + tl];
        }
        __syncthreads();
        for (int wb=0;wb<8;wb++){
            int w = wb*128 + wi;
            double2 gc2 = *(const double2*)&lds[w*6 + 2*tl2];
            double dv = d1[w];
            double ax = gc2.x*dv, ay = gc2.y*dv;
            int cnt = ccount[w];           // padded to multiple of 8
            const int* ci = cidx + (long)w*NN;
            const double* cv = cw + (long)w*NN;
            for (int e0=0; e0<cnt; e0+=8){
                #pragma unroll
                for (int k=0;k<8;k++){
                    double wt_ = cv[e0+k];
                    double2 s = *(const double2*)&lds[ci[e0+k]*6 + 2*tl2];
                    ax += wt_*s.x; ay += wt_*s.y;
                }
            }
            r1x[wb] = ax; r1y[wb] = ay;
        }
    }
    __syncthreads();
    // ---- dir 1: source P2[ch] ----
    {
        const double* src = P2 + base;
        for (int k=0;k<16;k++){
            int idx = k*256 + tid;
            int v = idx>>2, tl = idx&3;
            lds[v*6+tl] = src[(long)v*TTL + t0 + tl];
        }
        __syncthreads();
        for (int wb=0;wb<8;wb++){
            int w = wb*128 + wi;
            double2 gc2 = *(const double2*)&lds[w*6 + 2*tl2];
            double dv = d2[w];
            double ax = gc2.x*dv, ay = gc2.y*dv;
            const int* tc = topc + w*TOPK;
            const double* e2 = ew2 + w*TOPK;
            for (int r0=0;r0<TOPK;r0+=6){
                #pragma unroll
                for (int k=0;k<6;k++){
                    double wv = e2[r0+k];
                    double2 s = *(const double2*)&lds[tc[r0+k]*6 + 2*tl2];
                    ax += wv*s.x; ay += wv*s.y;   // wv==0 contributes exact 0
                }
            }
            long p = base + (long)w*TTL + t0 + 2*tl2;
            double2 rv; rv.x = r1x[wb] + ax; rv.y = r1y[wb] + ay;
            *(double2*)&Q12[p] = rv;
        }
    }
}

// decoder tail: e = P0 + Q12 -> relu -> fused (dout.w_end) dot -> fp32 [B,T,N]
__global__ __launch_bounds__(256) void k_dec_tail(const double* __restrict__ P0,
    const double* __restrict__ Q12,
    const double* __restrict__ Wt, float* __restrict__ out, long S, int b0)
{
    long p = (long)blockIdx.x*256 + threadIdx.x;
    double res = Wt[OBC];
    #pragma unroll 8
    for (int o2=0;o2<32;o2++){
        double e = P0[(long)o2*S+p] + Q12[(long)o2*S+p];
        e = e>0.0 ? e : 0.0;
        res += Wt[OWC+o2]*e;
    }
    int cb = (int)(p >> 17);
    long r = p & (NTP-1);
    int v = (int)(r >> 7), t = (int)(r & (TTL-1));
    out[((long)(b0+cb)*TTL + t)*NN + v] = (float)res;
}

// ============ launch ============

extern "C" void kernel_launch(void* const* d_in, const int* in_sizes, int n_in,
                              void* d_out, int out_size, void* d_ws, size_t ws_size,
                              hipStream_t stream)
{
    const float* x      = (const float*)d_in[0];
    const int*   idx    = (const int*)  d_in[1];
    const float* emb1   = (const float*)d_in[2];
    const float* emb2   = (const float*)d_in[3];
    const float* lin1_w = (const float*)d_in[4];
    const float* lin1_b = (const float*)d_in[5];
    const float* lin2_w = (const float*)d_in[6];
    const float* lin2_b = (const float*)d_in[7];
    const float* w_start= (const float*)d_in[8];
    const float* b_start= (const float*)d_in[9];
    const float* etf_w  = (const float*)d_in[10];
    const float* etf_b  = (const float*)d_in[11];
    const float* etg_w  = (const float*)d_in[12];
    const float* etg_b  = (const float*)d_in[13];
    const float* eg1_w  = (const float*)d_in[14];
    const float* eg1_b  = (const float*)d_in[15];
    const float* eg2_w  = (const float*)d_in[16];
    const float* eg2_b  = (const float*)d_in[17];
    const float* eend_w = (const float*)d_in[18];
    const float* eend_b = (const float*)d_in[19];
    const float* eout_w = (const float*)d_in[20];
    const float* eout_b = (const float*)d_in[21];
    const float* dtf_w  = (const float*)d_in[22];
    const float* dtf_b  = (const float*)d_in[23];
    const float* dtg_w  = (const float*)d_in[24];
    const float* dtg_b  = (const float*)d_in[25];
    const float* dg1_w  = (const float*)d_in[26];
    const float* dg1_b  = (const float*)d_in[27];
    const float* dg2_w  = (const float*)d_in[28];
    const float* dg2_b  = (const float*)d_in[29];
    const float* dend_w = (const float*)d_in[30];
    const float* dend_b = (const float*)d_in[31];
    const float* dout_w = (const float*)d_in[32];
    const float* dout_b = (const float*)d_in[33];
    const float* w_end  = (const float*)d_in[34];
    const float* b_end  = (const float*)d_in[35];
    float* out = (float*)d_out;

    char* basep = (char*)d_ws;
    size_t cur = 0;
    auto alloc = [&](size_t bytes)->void* {
        void* p = basep + cur;
        cur = (cur + bytes + 511) & ~(size_t)511;
        return p;
    };
    double* W     = (double*)alloc(WTOT*sizeof(double));
    double* n1    = (double*)alloc(65536*sizeof(double));
    double* n2    = (double*)alloc(65536*sizeof(double));
    double* topv  = (double*)alloc((size_t)NN*TOPK*sizeof(double));
    int*    topc  = (int*)   alloc((size_t)NN*TOPK*sizeof(int));
    double* rs1   = (double*)alloc(NN*sizeof(double));
    double* rs2   = (double*)alloc(NN*sizeof(double));
    double* colsum= (double*)alloc(NN*sizeof(double));
    double* d1a   = (double*)alloc(NN*sizeof(double));
    double* d2a   = (double*)alloc(NN*sizeof(double));
    double* ew2   = (double*)alloc((size_t)NN*TOPK*sizeof(double));
    int*    ccount= (int*)   alloc(NN*sizeof(int));
    int*    cidx  = (int*)   alloc((size_t)NN*NN*sizeof(int));
    double* cw    = (double*)alloc((size_t)NN*NN*sizeof(double));
    float*  xT    = (float*) alloc((size_t)16*NTP*sizeof(float));

    // plane arena: A(64) + B(48) + C(64) channel planes of CB*NTP doubles
    size_t perb = (size_t)176 * NTP * sizeof(double);
    int CB = 1;
    for (int c = 16; c >= 1; c >>= 1){
        if (cur + perb*(size_t)c <= ws_size){ CB = c; break; }
    }
    long S = (long)CB * NTP;
    double* A = (double*)alloc((size_t)64*S*sizeof(double));
    double* B = (double*)alloc((size_t)48*S*sizeof(double));
    double* C = (double*)alloc((size_t)64*S*sizeof(double));

    (void)hipMemsetAsync(colsum, 0, NN*sizeof(double), stream);
    (void)hipMemsetAsync(ccount, 0, NN*sizeof(int), stream);

    k_prep_weights<<<32,256,0,stream>>>(
        w_start,b_start, etf_w,etf_b, etg_w,etg_b, eg1_w,eg1_b, eg2_w,eg2_b,
        eend_w,eend_b, eout_w,eout_b, dtf_w,dtf_b, dtg_w,dtg_b, dg1_w,dg1_b,
        dg2_w,dg2_b, dend_w,dend_b, dout_w,dout_b, w_end,b_end, W);
    k_emb<<<256,256,0,stream>>>(idx, emb1, emb2, lin1_w, lin1_b, lin2_w, lin2_b, n1, n2);
    k_topk<<<NN,64,0,stream>>>(n1, n2, topc, topv, rs1, colsum);
    k_csc<<<4,256,0,stream>>>(topc, topv, rs1, ccount, cidx, cw);
    k_pad<<<4,256,0,stream>>>(ccount, cidx, cw);
    k_post1<<<4,256,0,stream>>>(colsum, rs1, rs2, d1a, d2a);
    k_post2<<<(NN*TOPK+255)/256,256,0,stream>>>(topc, topv, rs2, ew2);
    k_xT<<<dim3(4,32,16),dim3(32,8),0,stream>>>(x, xT);

    int nch = 16 / CB;
    for (int ch=0; ch<nch; ch++){
        int b0 = ch*CB;
        // encoder: fused gate+graph -> eg(B[0:16]), es1(B[16:32]), es2(B[32:48])
        k_enc_gg<<<dim3(32,16,CB),256,0,stream>>>(xT, B, B+(long)16*S, B+(long)32*S, W,
            ccount,cidx,cw, topc,ew2, d1a,d2a, S, b0);
        // encoder tail: B[0:48] -> e32 (A[0:32])
        k_enc_tail<<<512*CB,256,0,stream>>>(B, A, W, S);
        // decoder gate (eout folded): e32(A) -> g (C[0:64])
        k_dec_gate<<<2048*CB,256,0,stream>>>(A, C, W, S);
        // decoder fused-mix conv: g(C) -> P1,P2 (A[0:64]), P0 (B[0:32])
        k_dec_conv<<<dim3(512*CB,2),256,0,stream>>>(C, A, B, W, S);
        // decoder graph gather (both dirs): A(P1,P2) -> Q12 (C[0:32])
        k_graph32<<<dim3(32,32,CB),256,0,stream>>>(A, A+(long)32*S, C,
            ccount,cidx,cw, topc,ew2, d1a,d2a, S);
        // decoder tail -> out
        k_dec_tail<<<512*CB,256,0,stream>>>(B, C, W, out, S, b0);
    }
    (void)in_sizes; (void)n_in; (void)out_size;
}

// Round 19
// 7198.528 us; speedup vs baseline: 1.4298x; 1.0357x over previous
//
#include <hip/hip_runtime.h>
#include <math.h>

#define NN   1024
#define TTL  128
#define NTP  131072   // NN*TTL
#define TOPK 30

// ---- fp64 weight region offsets (in doubles) ----
#define OEGTF_T 0
#define OEGTF_C 48
#define OEGTF_B 96
#define OEGTG_T 112
#define OEGTG_C 160
#define OEGTG_B 208
#define OEE0    224
#define OEE1    736
#define OEE2    1248
#define OEEB    1760
#define OEOUT_W 1792
#define OEOUT_B 3840
#define ODTF_B  16192
#define ODTG_B  28544
#define ODEB    34752
#define OWC     34784
#define OBC     34816
#define ODEALL  59456   // [i][96]: [0:32]=E1, [32:64]=E2, [64:96]=E0 (6144)
#define ODTW2   65600   // folded (tconv.eout): [oc][j=32][96] f taps 0..47, g taps 48..95 (12288)
#define OCF     77888   // f per-tap consts [oc][o][k] (192)
#define OCG     78080   // g per-tap consts (192)
#define WTOT    78272

// ============ setup kernels ============

__global__ void k_prep_weights(
    const float* __restrict__ w_start, const float* __restrict__ b_start,
    const float* __restrict__ etf_w, const float* __restrict__ etf_b,
    const float* __restrict__ etg_w, const float* __restrict__ etg_b,
    const float* __restrict__ eg1_w, const float* __restrict__ eg1_b,
    const float* __restrict__ eg2_w, const float* __restrict__ eg2_b,
    const float* __restrict__ eend_w, const float* __restrict__ eend_b,
    const float* __restrict__ eout_w, const float* __restrict__ eout_b,
    const float* __restrict__ dtf_w, const float* __restrict__ dtf_b,
    const float* __restrict__ dtg_w, const float* __restrict__ dtg_b,
    const float* __restrict__ dg1_w, const float* __restrict__ dg1_b,
    const float* __restrict__ dg2_w, const float* __restrict__ dg2_b,
    const float* __restrict__ dend_w, const float* __restrict__ dend_b,
    const float* __restrict__ dout_w, const float* __restrict__ dout_b,
    const float* __restrict__ w_end, const float* __restrict__ b_end,
    double* __restrict__ W)
{
    int tid = blockIdx.x*blockDim.x + threadIdx.x;
    int nthr = gridDim.x*blockDim.x;
    // encoder gate collapsed through w_start: tap[o][k] = sum_i w[o,i,k]*ws[i]
    for (int id=tid; id<96; id+=nthr){
        int which = id/48; int r = id%48; int o = r/3, k = r%3;
        const float* w = which ? etg_w : etf_w;
        double t=0.0, c=0.0;
        for (int i=0;i<16;i++){
            double wv = (double)w[(o*16+i)*3+k];
            t += wv*(double)w_start[i];
            c += wv*(double)b_start[i];
        }
        W[(which?OEGTG_T:OEGTF_T)+o*3+k] = t;
        W[(which?OEGTG_C:OEGTF_C)+o*3+k] = c;
    }
    for (int i=tid;i<16;i+=nthr){
        W[OEGTF_B+i] = (double)etf_b[i];
        W[OEGTG_B+i] = (double)etg_b[i];
    }
    // encoder fused (mix . end) matrices: Ee_k[i][o2] = sum_o eend_w[o2][o]*Mk[i][o]
    for (int id=tid; id<512; id+=nthr){
        int i = id>>5, o2 = id&31;
        double s0=0.0, s1=0.0, s2=0.0;
        for (int o=0;o<16;o++){
            double m0 = (double)eg1_w[o*32+i] + (double)eg2_w[o*32+i]
                      + 0.05*((double)eg1_w[o*32+16+i] + (double)eg2_w[o*32+16+i]);
            double m1 = 0.95*(double)eg1_w[o*32+16+i];
            double m2 = 0.95*(double)eg2_w[o*32+16+i];
            double ew = (double)eend_w[o2*16+o];
            s0 += ew*m0; s1 += ew*m1; s2 += ew*m2;
        }
        W[OEE0+i*32+o2]=s0; W[OEE1+i*32+o2]=s1; W[OEE2+i*32+o2]=s2;
    }
    for (int o2=tid; o2<32; o2+=nthr){
        double s = (double)eend_b[o2];
        for (int o=0;o<16;o++) s += (double)eend_w[o2*16+o]*((double)eg1_b[o]+(double)eg2_b[o]);
        W[OEEB+o2] = s;
    }
    for (int i=tid;i<64;i+=nthr){
        W[ODTF_B+i]=(double)dtf_b[i]; W[ODTG_B+i]=(double)dtg_b[i];
    }
    // folded decoder tconv weights: W'[oc][j][q], q<48: f (o*3+k), q>=48: g
    for (int id=tid; id<12288; id+=nthr){
        int oc = id/3072; int rem = id%3072; int j = rem/96; int q = rem%96;
        const float* w = (q<48) ? dtf_w : dtg_w;
        int q2 = (q<48) ? q : q-48;
        int o = q2/3, k = q2%3;
        double s = 0.0;
        for (int i=0;i<64;i++)
            s += (double)w[((oc*16+o)*64+i)*3+k]*(double)eout_w[i*32+j];
        W[ODTW2+id] = s;
    }
    // per-tap constants from eout_b
    for (int id=tid; id<384; id+=nthr){
        int which = id/192; int r = id%192;
        int oc = r/48; int q = r%48; int o = q/3, k = q%3;
        const float* w = which ? dtg_w : dtf_w;
        double s = 0.0;
        for (int i=0;i<64;i++)
            s += (double)w[((oc*16+o)*64+i)*3+k]*(double)eout_b[i];
        W[(which?OCG:OCF) + oc*48 + o*3 + k] = s;
    }
    // decoder fused (mix . end) matrices, combined layout [i][96]
    for (int id=tid; id<6144; id+=nthr){
        int i = id/96, j = id%96;
        double s = 0.0;
        if (j < 32){
            int o2 = j;
            for (int o=0;o<64;o++){
                double m1 = 0.95*(double)dg1_w[o*128+64+i];
                s += (double)dend_w[o2*64+o]*m1;
            }
        } else if (j < 64){
            int o2 = j-32;
            for (int o=0;o<64;o++){
                double m2 = 0.95*(double)dg2_w[o*128+64+i];
                s += (double)dend_w[o2*64+o]*m2;
            }
        } else {
            int o2 = j-64;
            for (int o=0;o<64;o++){
                double m0 = (double)dg1_w[o*128+i] + (double)dg2_w[o*128+i]
                          + 0.05*((double)dg1_w[o*128+64+i] + (double)dg2_w[o*128+64+i]);
                s += (double)dend_w[o2*64+o]*m0;
            }
        }
        W[ODEALL+id] = s;
    }
    for (int o2=tid; o2<32; o2+=nthr){
        double s = (double)dend_b[o2];
        for (int o=0;o<64;o++) s += (double)dend_w[o2*64+o]*((double)dg1_b[o]+(double)dg2_b[o]);
        W[ODEB+o2] = s;
        double wc = 0.0;
        for (int o3=0;o3<16;o3++) wc += (double)w_end[o3]*(double)dout_w[o3*32+o2];
        W[OWC+o2] = wc;
    }
    if (tid==0){
        double bc = (double)b_end[0];
        for (int o3=0;o3<16;o3++) bc += (double)w_end[o3]*(double)dout_b[o3];
        W[OBC] = bc;
    }
}

__global__ void k_emb(const int* __restrict__ idxp,
                      const float* __restrict__ emb1, const float* __restrict__ emb2,
                      const float* __restrict__ l1w, const float* __restrict__ l1b,
                      const float* __restrict__ l2w, const float* __restrict__ l2b,
                      double* __restrict__ n1, double* __restrict__ n2)
{
    int id = blockIdx.x*blockDim.x + threadIdx.x;   // 65536
    int i = id>>6, d = id&63;
    int ii = idxp[i];
    double a1 = (double)l1b[d], a2 = (double)l2b[d];
    for (int k=0;k<64;k++){
        a1 += (double)emb1[ii*64+k]*(double)l1w[d*64+k];
        a2 += (double)emb2[ii*64+k]*(double)l2w[d*64+k];
    }
    n1[id] = tanh(3.0*a1);
    n2[id] = tanh(3.0*a2);
}

__global__ __launch_bounds__(64) void k_topk(
    const double* __restrict__ n1, const double* __restrict__ n2,
    int* __restrict__ topc, double* __restrict__ topv,
    double* __restrict__ rs1, double* __restrict__ colsum)
{
    __shared__ double arow[NN];
    __shared__ double sn1[64], sn2[64];
    int i = blockIdx.x, lane = threadIdx.x;
    sn1[lane] = n1[i*64+lane];
    sn2[lane] = n2[i*64+lane];
    __syncthreads();
    for (int jb=0;jb<16;jb++){
        int j = jb*64 + lane;
        const double* p2 = n2 + j*64;
        const double* p1 = n1 + j*64;
        double d1v=0.0, d2v=0.0;
        for (int d=0;d<64;d++){ d1v += sn1[d]*p2[d]; d2v += sn2[d]*p1[d]; }
        double a = tanh(3.0*(d1v - d2v));
        arow[j] = a>0.0 ? a : 0.0;
    }
    __syncthreads();
    double rsum = 0.0;
    for (int r=0;r<TOPK;r++){
        double bv = -2.0; int bj = 1<<30;
        for (int jb=0;jb<16;jb++){
            int j = jb*64+lane;
            double v = arow[j];
            if (v>bv || (v==bv && j<bj)){ bv=v; bj=j; }
        }
        for (int off=32; off>=1; off>>=1){
            double ov = __shfl_xor(bv, off, 64);
            int    oj = __shfl_xor(bj, off, 64);
            if (ov>bv || (ov==bv && oj<bj)){ bv=ov; bj=oj; }
        }
        if (lane == (bj & 63)) arow[bj] = -2.0;
        if (lane == 0){
            topc[i*TOPK+r] = bj;
            topv[i*TOPK+r] = bv;
            if (bv > 0.0) atomicAdd(&colsum[bj], bv);
        }
        rsum += (bv > 0.0 ? bv : 0.0);
        __syncthreads();
    }
    if (lane == 0) rs1[i] = 1.0 + rsum;
}

__global__ void k_csc(const int* __restrict__ topc, const double* __restrict__ topv,
                      const double* __restrict__ rs1,
                      int* __restrict__ ccount, int* __restrict__ cidx, double* __restrict__ cw)
{
    int w = blockIdx.x*blockDim.x + threadIdx.x;
    if (w >= NN) return;
    double rv = rs1[w];
    for (int r=0;r<TOPK;r++){
        double v = topv[w*TOPK+r];
        if (v > 0.0){
            int col = topc[w*TOPK+r];
            int pos = atomicAdd(&ccount[col], 1);
            cidx[(long)col*NN+pos] = w;
            cw  [(long)col*NN+pos] = v / rv;
        }
    }
}

// pad each column's edge list to a multiple of 8 with zero-weight edges
__global__ void k_pad(int* __restrict__ ccount, int* __restrict__ cidx, double* __restrict__ cw)
{
    int col = blockIdx.x*blockDim.x + threadIdx.x;
    if (col >= NN) return;
    int cnt = ccount[col];
    int padded = (cnt + 7) & ~7;
    for (int e = cnt; e < padded; e++){
        cidx[(long)col*NN + e] = 0;
        cw  [(long)col*NN + e] = 0.0;
    }
    ccount[col] = padded;
}

__global__ void k_post1(const double* __restrict__ colsum, const double* __restrict__ rs1,
                        double* __restrict__ rs2, double* __restrict__ d1, double* __restrict__ d2)
{
    int v = blockIdx.x*blockDim.x + threadIdx.x;
    if (v >= NN) return;
    double r2 = 1.0 + colsum[v];
    rs2[v] = r2;
    d2[v] = 1.0/r2;
    d1[v] = 1.0/rs1[v];
}

__global__ void k_post2(const int* __restrict__ topc, const double* __restrict__ topv,
                        const double* __restrict__ rs2, double* __restrict__ ew2)
{
    int e = blockIdx.x*blockDim.x + threadIdx.x;
    if (e >= NN*TOPK) return;
    double v = topv[e];
    ew2[e] = (v > 0.0) ? v / rs2[topc[e]] : 0.0;
}

// x[B,T,N] fp32 -> xT[B,N,T] fp32
__global__ __launch_bounds__(256) void k_xT(const float* __restrict__ x, float* __restrict__ xT)
{
    __shared__ float tile[32][33];
    int b = blockIdx.z, t0 = blockIdx.x*32, n0 = blockIdx.y*32;
    int tx = threadIdx.x, ty = threadIdx.y;
    const float* xb = x + (long)b*NTP;
    for (int r=0;r<4;r++){
        int tl = ty + 8*r;
        tile[tl][tx] = xb[(long)(t0+tl)*NN + n0 + tx];
    }
    __syncthreads();
    float* ob = xT + (long)b*NTP;
    for (int r=0;r<4;r++){
        int nl = ty + 8*r;
        ob[(long)(n0+nl)*TTL + t0 + tx] = tile[tx][nl];
    }
}

// ============ pipeline kernels (planes [ch][v][t]) ============

// encoder: gate (collapsed taps) fused into graph staging; t-tile=4, stride-6 LDS.
// Gather: one thread per w (4 t-values contiguous), metadata loaded once per w.
__global__ __launch_bounds__(256) void k_enc_gg(const float* __restrict__ xT,
    double* __restrict__ eg, double* __restrict__ es1, double* __restrict__ es2,
    const double* __restrict__ Wt,
    const int* __restrict__ ccount, const int* __restrict__ cidx, const double* __restrict__ cw,
    const int* __restrict__ topc, const double* __restrict__ ew2,
    const double* __restrict__ d1, const double* __restrict__ d2,
    long S, int b0)
{
    __shared__ double ldsg[NN*6];   // 48 KB, stride 6 (pad 2)
    int tid = threadIdx.x, c = blockIdx.y, cb = blockIdx.z, t0 = blockIdx.x*4;
    double ft[3], fc[3], gt[3], gcc[3];
    #pragma unroll
    for (int k=0;k<3;k++){
        ft[k]=Wt[OEGTF_T+c*3+k]; fc[k]=Wt[OEGTF_C+c*3+k];
        gt[k]=Wt[OEGTG_T+c*3+k]; gcc[k]=Wt[OEGTG_C+c*3+k];
    }
    double fb = Wt[OEGTF_B+c], gb = Wt[OEGTG_B+c];
    const float* xb = xT + (long)(b0+cb)*NTP;
    long base = (long)c*S + (long)cb*NTP;
    for (int k=0;k<16;k++){
        int idx = k*256 + tid;
        int v = idx>>2, tl = idx&3, t = t0+tl;
        const float* xp = xb + (long)v*TTL + t;
        double xc = (double)xp[0];
        double atf = fb + ft[1]*xc + fc[1];
        double atg = gb + gt[1]*xc + gcc[1];
        if (t>0){ double xl = (double)xp[-1]; atf += ft[0]*xl + fc[0]; atg += gt[0]*xl + gcc[0]; }
        if (t<TTL-1){ double xr = (double)xp[1]; atf += ft[2]*xr + fc[2]; atg += gt[2]*xr + gcc[2]; }
        double gv = tanh(atf)/(1.0+exp(-atg));
        ldsg[v*6+tl] = gv;
        eg[base + (long)v*TTL + t] = gv;
    }
    __syncthreads();
    for (int wb=0;wb<4;wb++){
        int w = wb*256 + tid;
        const double* gw = &ldsg[w*6];
        double g0=gw[0], g1=gw[1], g2=gw[2], g3=gw[3];
        long p = base + (long)w*TTL + t0;
        double dv = d1[w];
        double a0=g0*dv, a1=g1*dv, a2=g2*dv, a3=g3*dv;
        int cnt = ccount[w];               // padded to multiple of 8
        const int* ci = cidx + (long)w*NN;
        const double* cv = cw + (long)w*NN;
        for (int e0=0; e0<cnt; e0+=8){
            #pragma unroll
            for (int k=0;k<8;k++){
                double wt_ = cv[e0+k];
                const double* s = &ldsg[ci[e0+k]*6];
                a0 += wt_*s[0]; a1 += wt_*s[1]; a2 += wt_*s[2]; a3 += wt_*s[3];
            }
        }
        es1[p]=a0; es1[p+1]=a1; es1[p+2]=a2; es1[p+3]=a3;
        double d2v = d2[w];
        a0=g0*d2v; a1=g1*d2v; a2=g2*d2v; a3=g3*d2v;
        const int* tc = topc + w*TOPK;
        const double* e2 = ew2 + w*TOPK;
        for (int r0=0;r0<TOPK;r0+=6){
            #pragma unroll
            for (int k=0;k<6;k++){
                double wv = e2[r0+k];
                const double* s = &ldsg[tc[r0+k]*6];
                a0 += wv*s[0]; a1 += wv*s[1]; a2 += wv*s[2]; a3 += wv*s[3];
            }
        }
        es2[p]=a0; es2[p+1]=a1; es2[p+2]=a2; es2[p+3]=a3;
    }
}

// encoder tail: fused (mix.end) -> relu -> e32 planes (eout folded into dec_gate)
__global__ __launch_bounds__(256) void k_enc_tail(const double* __restrict__ Bp,
    double* __restrict__ E32, const double* __restrict__ Wt, long S)
{
    long p = (long)blockIdx.x*256 + threadIdx.x;
    double e[32];
    #pragma unroll
    for (int o2=0;o2<32;o2++) e[o2] = Wt[OEEB+o2];
    for (int i=0;i<16;i++){
        double a = Bp[(long)i*S+p], b = Bp[(long)(16+i)*S+p], c = Bp[(long)(32+i)*S+p];
        const double* w0 = Wt+OEE0+i*32;
        const double* w1 = Wt+OEE1+i*32;
        const double* w2 = Wt+OEE2+i*32;
        #pragma unroll
        for (int o2=0;o2<32;o2++) e[o2] += w0[o2]*a + w1[o2]*b + w2[o2]*c;
    }
    #pragma unroll
    for (int o2=0;o2<32;o2++){
        double v = e[o2];
        E32[(long)o2*S+p] = v>0.0 ? v : 0.0;
    }
}

// decoder gated tconv with eout folded in: K=32 e-channels x 3 taps.
// block = 2 v-strips x 128 t, XCD-aware oc map.
__global__ __launch_bounds__(256) void k_dec_gate(const double* __restrict__ E32,
    double* __restrict__ g, const double* __restrict__ Wt, long S)
{
    int bx = blockIdx.x;
    int oc = (bx >> 3) & 3;
    long vpair = (long)(bx >> 5)*8 + (bx & 7);
    int tid = threadIdx.x;
    int t = tid & 127, vv = tid >> 7;
    long vstrip = vpair*2 + vv;
    long pos = vstrip*TTL + t;
    bool hasL = (t>0), hasR = (t<TTL-1);
    double af[16], ag[16];
    #pragma unroll
    for (int o=0;o<16;o++){
        double bf = Wt[ODTF_B+oc*16+o] + Wt[OCF+oc*48+o*3+1];
        double bg = Wt[ODTG_B+oc*16+o] + Wt[OCG+oc*48+o*3+1];
        if (hasL){ bf += Wt[OCF+oc*48+o*3];   bg += Wt[OCG+oc*48+o*3]; }
        if (hasR){ bf += Wt[OCF+oc*48+o*3+2]; bg += Wt[OCG+oc*48+o*3+2]; }
        af[o]=bf; ag[o]=bg;
    }
    #pragma unroll 1
    for (int j=0;j<32;j++){
        const double* xp = E32 + (long)j*S + pos;
        double xc = xp[0];
        double xl = hasL ? xp[-1] : 0.0;
        double xr = hasR ? xp[1]  : 0.0;
        const double* wfg = Wt + ODTW2 + (long)(oc*32+j)*96;
        #pragma unroll
        for (int o=0;o<16;o++){
            af[o] += wfg[o*3]*xl + wfg[o*3+1]*xc + wfg[o*3+2]*xr;
            ag[o] += wfg[48+o*3]*xl + wfg[48+o*3+1]*xc + wfg[48+o*3+2]*xr;
        }
    }
    #pragma unroll
    for (int o=0;o<16;o++){
        g[(long)(oc*16+o)*S + pos] = tanh(af[o])/(1.0+exp(-ag[o]));
    }
}

// decoder fused-mix pointwise conv, merged 2-pass: jc0 -> P1+P2 (one g read),
// jc1 -> P0. Weight rows uniform.
__global__ __launch_bounds__(256) void k_dec_conv(const double* __restrict__ g,
    double* __restrict__ Cp, double* __restrict__ P0p,
    const double* __restrict__ Wt, long S)
{
    long p = (long)blockIdx.x*256 + threadIdx.x;
    int jc = blockIdx.y;
    if (jc == 0){
        double a1[32], a2[32];
        #pragma unroll
        for (int jj=0;jj<32;jj++){ a1[jj]=0.0; a2[jj]=0.0; }
        #pragma unroll 1
        for (int i=0;i<64;i++){
            double gv = g[(long)i*S+p];
            const double* wr = Wt + ODEALL + i*96;
            #pragma unroll
            for (int jj=0;jj<32;jj++){ a1[jj] += wr[jj]*gv; a2[jj] += wr[32+jj]*gv; }
        }
        #pragma unroll
        for (int jj=0;jj<32;jj++){
            Cp[(long)jj*S+p] = a1[jj];
            Cp[(long)(32+jj)*S+p] = a2[jj];
        }
    } else {
        double a0[32];
        #pragma unroll
        for (int jj=0;jj<32;jj++) a0[jj] = Wt[ODEB+jj];
        #pragma unroll 1
        for (int i=0;i<64;i++){
            double gv = g[(long)i*S+p];
            const double* wr = Wt + ODEALL + i*96 + 64;
            #pragma unroll
            for (int jj=0;jj<32;jj++) a0[jj] += wr[jj]*gv;
        }
        #pragma unroll
        for (int jj=0;jj<32;jj++) P0p[(long)jj*S+p] = a0[jj];
    }
}

// decoder graph gather, BOTH dirs per block, one thread per w (4 t contiguous):
// stage P1[ch] -> dir-0 partials, restage P2[ch] -> dir-1, write summed Q12 once.
__global__ __launch_bounds__(256) void k_graph32(const double* __restrict__ P1,
    const double* __restrict__ P2, double* __restrict__ Q12,
    const int* __restrict__ ccount, const int* __restrict__ cidx, const double* __restrict__ cw,
    const int* __restrict__ topc, const double* __restrict__ ew2,
    const double* __restrict__ d1, const double* __restrict__ d2, long S)
{
    __shared__ double lds[NN*6];   // 48 KB
    int tid = threadIdx.x;
    int ch = blockIdx.y;           // 0..31
    int cb = blockIdx.z;
    long base = (long)ch*S + (long)cb*NTP;
    int t0 = blockIdx.x*4;
    double r0[4], r1[4], r2[4], r3[4];
    // ---- dir 0: source P1[ch] ----
    {
        const double* src = P1 + base;
        for (int k=0;k<16;k++){
            int idx = k*256 + tid;
            int v = idx>>2, tl = idx&3;
            lds[v*6+tl] = src[(long)v*TTL + t0 + tl];
        }
        __syncthreads();
        for (int wb=0;wb<4;wb++){
            int w = wb*256 + tid;
            const double* gw = &lds[w*6];
            double dv = d1[w];
            double a0=gw[0]*dv, a1=gw[1]*dv, a2=gw[2]*dv, a3=gw[3]*dv;
            int cnt = ccount[w];           // padded to multiple of 8
            const int* ci = cidx + (long)w*NN;
            const double* cv = cw + (long)w*NN;
            for (int e0=0; e0<cnt; e0+=8){
                #pragma unroll
                for (int k=0;k<8;k++){
                    double wt_ = cv[e0+k];
                    const double* s = &lds[ci[e0+k]*6];
                    a0 += wt_*s[0]; a1 += wt_*s[1]; a2 += wt_*s[2]; a3 += wt_*s[3];
                }
            }
            r0[wb]=a0; r1[wb]=a1; r2[wb]=a2; r3[wb]=a3;
        }
    }
    __syncthreads();
    // ---- dir 1: source P2[ch] ----
    {
        const double* src = P2 + base;
        for (int k=0;k<16;k++){
            int idx = k*256 + tid;
            int v = idx>>2, tl = idx&3;
            lds[v*6+tl] = src[(long)v*TTL + t0 + tl];
        }
        __syncthreads();
        for (int wb=0;wb<4;wb++){
            int w = wb*256 + tid;
            const double* gw = &lds[w*6];
            double dv = d2[w];
            double a0=gw[0]*dv, a1=gw[1]*dv, a2=gw[2]*dv, a3=gw[3]*dv;
            const int* tc = topc + w*TOPK;
            const double* e2 = ew2 + w*TOPK;
            for (int q0=0;q0<TOPK;q0+=6){
                #pragma unroll
                for (int k=0;k<6;k++){
                    double wv = e2[q0+k];
                    const double* s = &lds[tc[q0+k]*6];
                    a0 += wv*s[0]; a1 += wv*s[1]; a2 += wv*s[2]; a3 += wv*s[3];
                }
            }
            long p = base + (long)w*TTL + t0;
            Q12[p]   = r0[wb] + a0;
            Q12[p+1] = r1[wb] + a1;
            Q12[p+2] = r2[wb] + a2;
            Q12[p+3] = r3[wb] + a3;
        }
    }
}

// decoder tail: e = P0 + Q12 -> relu -> fused (dout.w_end) dot -> fp32 [B,T,N]
__global__ __launch_bounds__(256) void k_dec_tail(const double* __restrict__ P0,
    const double* __restrict__ Q12,
    const double* __restrict__ Wt, float* __restrict__ out, long S, int b0)
{
    long p = (long)blockIdx.x*256 + threadIdx.x;
    double res = Wt[OBC];
    #pragma unroll 8
    for (int o2=0;o2<32;o2++){
        double e = P0[(long)o2*S+p] + Q12[(long)o2*S+p];
        e = e>0.0 ? e : 0.0;
        res += Wt[OWC+o2]*e;
    }
    int cb = (int)(p >> 17);
    long r = p & (NTP-1);
    int v = (int)(r >> 7), t = (int)(r & (TTL-1));
    out[((long)(b0+cb)*TTL + t)*NN + v] = (float)res;
}

// ============ launch ============

extern "C" void kernel_launch(void* const* d_in, const int* in_sizes, int n_in,
                              void* d_out, int out_size, void* d_ws, size_t ws_size,
                              hipStream_t stream)
{
    const float* x      = (const float*)d_in[0];
    const int*   idx    = (const int*)  d_in[1];
    const float* emb1   = (const float*)d_in[2];
    const float* emb2   = (const float*)d_in[3];
    const float* lin1_w = (const float*)d_in[4];
    const float* lin1_b = (const float*)d_in[5];
    const float* lin2_w = (const float*)d_in[6];
    const float* lin2_b = (const float*)d_in[7];
    const float* w_start= (const float*)d_in[8];
    const float* b_start= (const float*)d_in[9];
    const float* etf_w  = (const float*)d_in[10];
    const float* etf_b  = (const float*)d_in[11];
    const float* etg_w  = (const float*)d_in[12];
    const float* etg_b  = (const float*)d_in[13];
    const float* eg1_w  = (const float*)d_in[14];
    const float* eg1_b  = (const float*)d_in[15];
    const float* eg2_w  = (const float*)d_in[16];
    const float* eg2_b  = (const float*)d_in[17];
    const float* eend_w = (const float*)d_in[18];
    const float* eend_b = (const float*)d_in[19];
    const float* eout_w = (const float*)d_in[20];
    const float* eout_b = (const float*)d_in[21];
    const float* dtf_w  = (const float*)d_in[22];
    const float* dtf_b  = (const float*)d_in[23];
    const float* dtg_w  = (const float*)d_in[24];
    const float* dtg_b  = (const float*)d_in[25];
    const float* dg1_w  = (const float*)d_in[26];
    const float* dg1_b  = (const float*)d_in[27];
    const float* dg2_w  = (const float*)d_in[28];
    const float* dg2_b  = (const float*)d_in[29];
    const float* dend_w = (const float*)d_in[30];
    const float* dend_b = (const float*)d_in[31];
    const float* dout_w = (const float*)d_in[32];
    const float* dout_b = (const float*)d_in[33];
    const float* w_end  = (const float*)d_in[34];
    const float* b_end  = (const float*)d_in[35];
    float* out = (float*)d_out;

    char* basep = (char*)d_ws;
    size_t cur = 0;
    auto alloc = [&](size_t bytes)->void* {
        void* p = basep + cur;
        cur = (cur + bytes + 511) & ~(size_t)511;
        return p;
    };
    double* W     = (double*)alloc(WTOT*sizeof(double));
    double* n1    = (double*)alloc(65536*sizeof(double));
    double* n2    = (double*)alloc(65536*sizeof(double));
    double* topv  = (double*)alloc((size_t)NN*TOPK*sizeof(double));
    int*    topc  = (int*)   alloc((size_t)NN*TOPK*sizeof(int));
    double* rs1   = (double*)alloc(NN*sizeof(double));
    double* rs2   = (double*)alloc(NN*sizeof(double));
    double* colsum= (double*)alloc(NN*sizeof(double));
    double* d1a   = (double*)alloc(NN*sizeof(double));
    double* d2a   = (double*)alloc(NN*sizeof(double));
    double* ew2   = (double*)alloc((size_t)NN*TOPK*sizeof(double));
    int*    ccount= (int*)   alloc(NN*sizeof(int));
    int*    cidx  = (int*)   alloc((size_t)NN*NN*sizeof(int));
    double* cw    = (double*)alloc((size_t)NN*NN*sizeof(double));
    float*  xT    = (float*) alloc((size_t)16*NTP*sizeof(float));

    // plane arena: A(64) + B(48) + C(64) channel planes of CB*NTP doubles
    size_t perb = (size_t)176 * NTP * sizeof(double);
    int CB = 1;
    for (int c = 16; c >= 1; c >>= 1){
        if (cur + perb*(size_t)c <= ws_size){ CB = c; break; }
    }
    long S = (long)CB * NTP;
    double* A = (double*)alloc((size_t)64*S*sizeof(double));
    double* B = (double*)alloc((size_t)48*S*sizeof(double));
    double* C = (double*)alloc((size_t)64*S*sizeof(double));

    (void)hipMemsetAsync(colsum, 0, NN*sizeof(double), stream);
    (void)hipMemsetAsync(ccount, 0, NN*sizeof(int), stream);

    k_prep_weights<<<32,256,0,stream>>>(
        w_start,b_start, etf_w,etf_b, etg_w,etg_b, eg1_w,eg1_b, eg2_w,eg2_b,
        eend_w,eend_b, eout_w,eout_b, dtf_w,dtf_b, dtg_w,dtg_b, dg1_w,dg1_b,
        dg2_w,dg2_b, dend_w,dend_b, dout_w,dout_b, w_end,b_end, W);
    k_emb<<<256,256,0,stream>>>(idx, emb1, emb2, lin1_w, lin1_b, lin2_w, lin2_b, n1, n2);
    k_topk<<<NN,64,0,stream>>>(n1, n2, topc, topv, rs1, colsum);
    k_csc<<<4,256,0,stream>>>(topc, topv, rs1, ccount, cidx, cw);
    k_pad<<<4,256,0,stream>>>(ccount, cidx, cw);
    k_post1<<<4,256,0,stream>>>(colsum, rs1, rs2, d1a, d2a);
    k_post2<<<(NN*TOPK+255)/256,256,0,stream>>>(topc, topv, rs2, ew2);
    k_xT<<<dim3(4,32,16),dim3(32,8),0,stream>>>(x, xT);

    int nch = 16 / CB;
    for (int ch=0; ch<nch; ch++){
        int b0 = ch*CB;
        // encoder: fused gate+graph -> eg(B[0:16]), es1(B[16:32]), es2(B[32:48])
        k_enc_gg<<<dim3(32,16,CB),256,0,stream>>>(xT, B, B+(long)16*S, B+(long)32*S, W,
            ccount,cidx,cw, topc,ew2, d1a,d2a, S, b0);
        // encoder tail: B[0:48] -> e32 (A[0:32])
        k_enc_tail<<<512*CB,256,0,stream>>>(B, A, W, S);
        // decoder gate (eout folded): e32(A) -> g (C[0:64])
        k_dec_gate<<<2048*CB,256,0,stream>>>(A, C, W, S);
        // decoder fused-mix conv: g(C) -> P1,P2 (A[0:64]), P0 (B[0:32])
        k_dec_conv<<<dim3(512*CB,2),256,0,stream>>>(C, A, B, W, S);
        // decoder graph gather (both dirs): A(P1,P2) -> Q12 (C[0:32])
        k_graph32<<<dim3(32,32,CB),256,0,stream>>>(A, A+(long)32*S, C,
            ccount,cidx,cw, topc,ew2, d1a,d2a, S);
        // decoder tail -> out
        k_dec_tail<<<512*CB,256,0,stream>>>(B, C, W, out, S, b0);
    }
    (void)in_sizes; (void)n_in; (void)out_size;
}